// Round 2
// baseline (23.507 us; speedup 1.0000x reference)
//
#include <hip/hip_runtime.h>
#include <math.h>

#define MM 8192
#define NN 64
#define NB 25
#define WAVES 4

__device__ __forceinline__ float rl(float x, int b) {
    return __int_as_float(__builtin_amdgcn_readlane(__float_as_int(x), b));
}
__device__ __forceinline__ float rfl(float x) {
    return __int_as_float(__builtin_amdgcn_readfirstlane(__float_as_int(x)));
}

struct Q { float w, x, y, z; };

__device__ __forceinline__ Q qmul(const Q a, const Q b) {
    Q r;
    r.w = a.w*b.w - a.x*b.x - a.y*b.y - a.z*b.z;
    r.x = a.w*b.x + b.w*a.x + a.y*b.z - a.z*b.y;
    r.y = a.w*b.y + b.w*a.y + a.z*b.x - a.x*b.z;
    r.z = a.w*b.z + b.w*a.z + a.x*b.y - a.y*b.x;
    return r;
}

__global__ __launch_bounds__(WAVES*64) void skin_kernel(
    const float* __restrict__ xyz,
    const float* __restrict__ t_qr,
    const float* __restrict__ t_qd,
    const float* __restrict__ rest_qr,
    const float* __restrict__ rest_qd,
    const float* __restrict__ log_gauss,
    float* __restrict__ out)
{
    const int wave = threadIdx.x >> 6;
    const int lane = threadIdx.x & 63;
    const int m = blockIdx.x * WAVES + wave;
    const int bl = (lane < NB) ? lane : (NB - 1);   // uniform control flow; lanes 25..63 duplicate bone 24

    // ---------------- per-bone prep, one bone per lane, all in VGPRs ----------------
    const int qbase = (m * NB + bl) * 4;
    const float4 Tqv = *reinterpret_cast<const float4*>(t_qr + qbase);
    const float4 Tdv = *reinterpret_cast<const float4*>(t_qd + qbase);
    const float4 Rqv = *reinterpret_cast<const float4*>(rest_qr + qbase);
    const float4 Rdv = *reinterpret_cast<const float4*>(rest_qd + qbase);
    const float i0 = __expf(-log_gauss[bl * 3 + 0]);
    const float i1 = __expf(-log_gauss[bl * 3 + 1]);
    const float i2 = __expf(-log_gauss[bl * 3 + 2]);

    const Q Tq{Tqv.x, Tqv.y, Tqv.z, Tqv.w};
    const Q Td{Tdv.x, Tdv.y, Tdv.z, Tdv.w};
    const Q Rq{Rqv.x, Rqv.y, Rqv.z, Rqv.w};
    const Q Rqc{Rq.w, -Rq.x, -Rq.y, -Rq.z};
    const Q Rdc{Rdv.x, -Rdv.y, -Rdv.z, -Rdv.w};

    // se3 = t_art * inverse(rest_art)
    const Q se_r = qmul(Tq, Rqc);
    const Q m1 = qmul(Tq, Rdc);
    const Q m2 = qmul(Td, Rqc);
    const Q se_d{m1.w + m2.w, m1.x + m2.x, m1.y + m2.y, m1.z + m2.z};

    // hemisphere sign vs bone 0 (lane 0 holds bone 0; sign(0) -> +1)
    const float d0 = se_r.w * rfl(se_r.w) + se_r.x * rfl(se_r.x)
                   + se_r.y * rfl(se_r.y) + se_r.z * rfl(se_r.z);
    const float sg = (d0 < 0.f) ? -1.f : 1.f;
    const float qrw = sg * se_r.w, qrx = sg * se_r.x, qry = sg * se_r.y, qrz = sg * se_r.z;
    const float qdw = sg * se_d.w, qdx = sg * se_d.x, qdy = sg * se_d.y, qdz = sg * se_d.z;

    // bone-inverse transform: rot = R(qconj(rest_qr)), trans = 2*vec(qmul(qconj(rest_qd), rest_qr))
    const Q tqb = qmul(Rdc, Rq);
    const float tbx = 2.f * tqb.x, tby = 2.f * tqb.y, tbz = 2.f * tqb.z;

    const float qw = Rqc.w, qx = Rqc.x, qy = Rqc.y, qz = Rqc.z;
    const float r00 = 1.f - 2.f*(qy*qy + qz*qz), r01 = 2.f*(qx*qy - qw*qz), r02 = 2.f*(qx*qz + qw*qy);
    const float r10 = 2.f*(qx*qy + qw*qz), r11 = 1.f - 2.f*(qx*qx + qz*qz), r12 = 2.f*(qy*qz - qw*qx);
    const float r20 = 2.f*(qx*qz - qw*qy), r21 = 2.f*(qy*qz + qw*qx), r22 = 1.f - 2.f*(qx*qx + qy*qy);

    // G = S^-1 R (rows scaled), u = S^-1 t
    const float g00 = r00*i0, g01 = r01*i0, g02 = r02*i0;
    const float g10 = r10*i1, g11 = r11*i1, g12 = r12*i1;
    const float g20 = r20*i2, g21 = r21*i2, g22 = r22*i2;
    const float u0 = tbx*i0, u1 = tby*i1, u2 = tbz*i2;

    // logit(p) = -0.5*|Gp+u|^2 as a quadratic form with -0.5 folded in
    const float k0 = -0.5f*(g00*g00 + g10*g10 + g20*g20);
    const float k1 = -0.5f*(g01*g01 + g11*g11 + g21*g21);
    const float k2 = -0.5f*(g02*g02 + g12*g12 + g22*g22);
    const float k3 = -(g00*g01 + g10*g11 + g20*g21);
    const float k4 = -(g00*g02 + g10*g12 + g20*g22);
    const float k5 = -(g01*g02 + g11*g12 + g21*g22);
    const float k6 = -(g00*u0 + g10*u1 + g20*u2);
    const float k7 = -(g01*u0 + g11*u1 + g21*u2);
    const float k8 = -(g02*u0 + g12*u1 + g22*u2);
    const float k9 = -0.5f*(u0*u0 + u1*u1 + u2*u2);

    // ---------------- per-point main loop; bone constants via v_readlane (SGPR) ----------------
    const int pbase = (m * NN + lane) * 3;
    const float px = xyz[pbase], py = xyz[pbase + 1], pz = xyz[pbase + 2];
    const float fxx = px*px, fyy = py*py, fzz = pz*pz;
    const float fxy = px*py, fxz = px*pz, fyz = py*pz;

    float logit[NB];
    float mx = -3.4e38f;
#pragma unroll
    for (int b = 0; b < NB; ++b) {
        float t = fmaf(rl(k8, b), pz, rl(k9, b));
        t = fmaf(rl(k7, b), py, t);
        t = fmaf(rl(k6, b), px, t);
        t = fmaf(rl(k5, b), fyz, t);
        t = fmaf(rl(k4, b), fxz, t);
        t = fmaf(rl(k3, b), fxy, t);
        t = fmaf(rl(k2, b), fzz, t);
        t = fmaf(rl(k1, b), fyy, t);
        t = fmaf(rl(k0, b), fxx, t);
        logit[b] = t;
        mx = fmaxf(mx, t);
    }

    // blend with unnormalized weights (softmax denominator cancels under qr-normalization)
    float aw = 0.f, ax = 0.f, ay = 0.f, az = 0.f;
    float bw = 0.f, bx = 0.f, by = 0.f, bz = 0.f;
#pragma unroll
    for (int b = 0; b < NB; ++b) {
        const float e = __expf(logit[b] - mx);
        aw = fmaf(e, rl(qrw, b), aw);
        ax = fmaf(e, rl(qrx, b), ax);
        ay = fmaf(e, rl(qry, b), ay);
        az = fmaf(e, rl(qrz, b), az);
        bw = fmaf(e, rl(qdw, b), bw);
        bx = fmaf(e, rl(qdx, b), bx);
        by = fmaf(e, rl(qdy, b), by);
        bz = fmaf(e, rl(qdz, b), bz);
    }

    const float inv = rsqrtf(aw*aw + ax*ax + ay*ay + az*az);
    const Q qr{aw*inv, ax*inv, ay*inv, az*inv};
    const Q qd{bw*inv, bx*inv, by*inv, bz*inv};
    const Q qrc{qr.w, -qr.x, -qr.y, -qr.z};
    const Q tq = qmul(qd, qrc);

    const float uvx = qr.y*pz - qr.z*py;
    const float uvy = qr.z*px - qr.x*pz;
    const float uvz = qr.x*py - qr.y*px;
    const float cx = qr.y*uvz - qr.z*uvy;
    const float cy = qr.z*uvx - qr.x*uvz;
    const float cz = qr.x*uvy - qr.y*uvx;

    out[pbase]     = px + 2.f*(qr.w*uvx + cx) + 2.f*tq.x;
    out[pbase + 1] = py + 2.f*(qr.w*uvy + cy) + 2.f*tq.y;
    out[pbase + 2] = pz + 2.f*(qr.w*uvz + cz) + 2.f*tq.z;
}

extern "C" void kernel_launch(void* const* d_in, const int* in_sizes, int n_in,
                              void* d_out, int out_size, void* d_ws, size_t ws_size,
                              hipStream_t stream) {
    const float* xyz       = (const float*)d_in[0];
    const float* t_qr      = (const float*)d_in[1];
    const float* t_qd      = (const float*)d_in[2];
    const float* rest_qr   = (const float*)d_in[3];
    const float* rest_qd   = (const float*)d_in[4];
    const float* log_gauss = (const float*)d_in[5];
    float* out = (float*)d_out;

    dim3 grid(MM / WAVES);
    dim3 block(WAVES * 64);
    hipLaunchKernelGGL(skin_kernel, grid, block, 0, stream,
                       xyz, t_qr, t_qd, rest_qr, rest_qd, log_gauss, out);
}